// Round 16
// baseline (42.497 us; speedup 1.0000x reference)
//
#include <hip/hip_runtime.h>

typedef unsigned short u16;
typedef unsigned int u32;
typedef _Float16 f16x8 __attribute__((ext_vector_type(8)));
typedef float f32x16 __attribute__((ext_vector_type(16)));

#define B_ 8
#define C_ 64
#define H_ 112
#define W_ 112
#define HW_ 12544
#define F_ 128
#define OH_ 110
#define OW_ 110
#define OWOH 12100
#define NPOS 96800
#define KK_ 576
#define NT_ 384           // output positions per block
#define NBLK 253          // ceil(NPOS/NT_) blocks of 512 threads (128f x 384n)
#define OCTSTRIDE 802816  // B_*W_*H_*8 elems per c-oct plane
#define AELEMS 73728      // F_*KK_ fp16 elems (kT total)
#define COLS 10           // staged input cols (<=9 needed incl b-crossing + halo)
#define COLE 896          // elems per col = 112*8
#define OCTE (COLS * COLE)   // 8960 elems per oct per buffer
#define BUFE (4 * OCTE)      // 35840 elems per half-buffer; 2 bufs = 143KB LDS

__device__ __forceinline__ void gl_lds16(const void* g, void* l) {
  __builtin_amdgcn_global_load_lds((const __attribute__((address_space(1))) void*)g,
                                   (__attribute__((address_space(3))) void*)l,
                                   16, 0, 0);
}

// ---- fused prep: blocks 0..895 transpose input; blocks 896..931 convert kernel ----
// (unchanged layouts: xT [c_oct][b][w][h]{8c}; kT A'[ko16][khalf][128f][8c])
__global__ __launch_bounds__(256) void prep_all(const float* __restrict__ in,
                                                const float* __restrict__ k,
                                                u16* __restrict__ xT,
                                                u16* __restrict__ kT) {
  const int bid = blockIdx.x;
  const int tid = threadIdx.x;
  if (bid >= 896) {
    const int base = (bid - 896) * 2048;
#pragma unroll
    for (int t = 0; t < 8; ++t) {
      int idx = base + t * 256 + tid;
      int c = idx & 7;
      int f = (idx >> 3) & 127;
      int hf = (idx >> 10) & 1;
      int ko16 = idx >> 11;
      _Float16 h = (_Float16)k[f * KK_ + ko16 * 16 + hf * 8 + c];
      kT[idx] = __builtin_bit_cast(u16, h);
    }
    return;
  }
  __shared__ float tile[8][8][113];
  const int b = bid / 112;
  const int r = bid % 112;
  const int oct = r / 14;
  const int hs = (r % 14) * 8;

  for (int idx = tid; idx < 8 * 8 * 112; idx += 256) {
    int c = idx / 896;
    int rem = idx - c * 896;
    int h = rem / 112;
    int w = rem - h * 112;
    tile[c][h][w] = in[(((size_t)(b * 64 + oct * 8 + c)) * 112 + (hs + h)) * 112 + w];
  }
  __syncthreads();

  for (int idx = tid; idx < 896; idx += 256) {
    int w = idx >> 3;
    int h = idx & 7;
    f16x8 v;
#pragma unroll
    for (int c = 0; c < 8; ++c) v[c] = (_Float16)tile[c][h][w];
    size_t o = ((((size_t)oct * B_ + b) * W_ + w) * H_ + (hs + h)) * 8;
    *(f16x8*)(xT + o) = v;
  }
}

// ---------------- main: 128f x 384n per 512-thr block; B WINDOW IN LDS ----------------
// r14 counters: 80MB/pass L2-miss = each block re-streams its input window 18x with
// zero cross-block sharing. Fix: stage the window ONCE per half (linear gl_lds,
// 4 oct x 10 col x 112 h x 16B = 57KB/buf, dbuf 143KB); tap shifts become LDS offsets.
// A (kT 144KB, chip-shared -> L2/L1-hot) streams per-tap, 512B-contiguous per halfwave.
// Global B traffic: 221MB -> 29MB one-shot. 8 waves (2 fgroups x 4 nwaves), 253 blocks.
__global__ __launch_bounds__(512, 2) void conv_mfma(
    const u16* __restrict__ xT, const u16* __restrict__ kT,
    float* __restrict__ out) {
  __shared__ u16 lds[2 * BUFE];  // 143360B

  const int tid = threadIdx.x;
  const int wave = tid >> 6;
  const int lane = tid & 63;
  const int l31 = lane & 31;
  const int hi = lane >> 5;
  const int fg = wave >> 2;   // f-group: 0 -> f0..63, 1 -> f64..127
  const int nw = wave & 3;    // n-wave

  const int nblk = blockIdx.x;
  const int n0b = nblk * NT_;
  const int b0 = n0b / OWOH;
  const int r0 = n0b - b0 * OWOH;
  const int w0 = r0 / OH_;
  const int g0 = b0 * W_ + w0;  // first staged input column (global col = b*112+w)

  // per-lane output positions: local col (vs g0) and h; clamp keeps in-window
  int narr[3], lcb[3], hh[3];
#pragma unroll
  for (int ni = 0; ni < 3; ++ni) {
    int n = n0b + nw * 96 + ni * 32 + l31;
    narr[ni] = n;
    int nc = n < NPOS ? n : NPOS - 1;
    int b = nc / OWOH;
    int r = nc - b * OWOH;
    int w = r / OH_;
    int h = r - w * OH_;
    lcb[ni] = b * W_ + w - g0;  // 0..6
    hh[ni] = h;
  }

  auto STAGE = [&](int half, int d) {
    // 4 octs x 1120 16B-chunks = 4480 chunks; 512 threads x 9 its
#pragma unroll
    for (int it = 0; it < 9; ++it) {
      int m = it * 512 + tid;
      if (m < 4480) {
        int oct4 = m / 1120;
        int rest = m - oct4 * 1120;
        const u16* src = xT + (half * 4 + oct4) * OCTSTRIDE + g0 * COLE + rest * 8;
        gl_lds16(src, &lds[d * BUFE + oct4 * OCTE + rest * 8]);
      }
    }
  };

  f32x16 acc[2][3] = {};

#define COMPUTE(TAP, HALF, D)                                                          \
  {                                                                                    \
    const int i_ = (TAP) / 3, j_ = (TAP) - i_ * 3;                                     \
    f16x8 ah[4];                                                                       \
    _Pragma("unroll") for (int t = 0; t < 2; ++t)                                      \
        _Pragma("unroll") for (int mi = 0; mi < 2; ++mi)                               \
            ah[t * 2 + mi] = *(const f16x8*)(kT +                                      \
            ((((((TAP) * 4 + (HALF) * 2 + t) * 2 + hi) << 7) + fg * 64 + mi * 32 + l31) \
             << 3));                                                                   \
    f16x8 bh[6];                                                                       \
    _Pragma("unroll") for (int ni = 0; ni < 3; ++ni)                                   \
        _Pragma("unroll") for (int t = 0; t < 2; ++t)                                  \
            bh[ni * 2 + t] = *(const f16x8*)&lds[(D) * BUFE + (t * 2 + hi) * OCTE +    \
                                                 (lcb[ni] + i_) * COLE +               \
                                                 (hh[ni] + j_) * 8];                   \
    _Pragma("unroll") for (int t = 0; t < 2; ++t)                                      \
        _Pragma("unroll") for (int mi = 0; mi < 2; ++mi)                               \
            _Pragma("unroll") for (int ni = 0; ni < 3; ++ni)                           \
                acc[mi][ni] = __builtin_amdgcn_mfma_f32_32x32x16_f16(                  \
                    ah[t * 2 + mi], bh[ni * 2 + t], acc[mi][ni], 0, 0, 0);             \
  }

  STAGE(0, 0);
  __syncthreads();  // buf0 visible

  COMPUTE(0, 0, 0)
  COMPUTE(1, 0, 0)
  COMPUTE(2, 0, 0)
  STAGE(1, 1);      // fires under taps 3..8 of half 0
  COMPUTE(3, 0, 0)
  COMPUTE(4, 0, 0)
  COMPUTE(5, 0, 0)
  COMPUTE(6, 0, 0)
  COMPUTE(7, 0, 0)
  COMPUTE(8, 0, 0)
  __syncthreads();  // buf1 visible (drains vmcnt)
  COMPUTE(0, 1, 1)
  COMPUTE(1, 1, 1)
  COMPUTE(2, 1, 1)
  COMPUTE(3, 1, 1)
  COMPUTE(4, 1, 1)
  COMPUTE(5, 1, 1)
  COMPUTE(6, 1, 1)
  COMPUTE(7, 1, 1)
  COMPUTE(8, 1, 1)
#undef COMPUTE

  // epilogue: col = lane&31 -> n; row = (reg&3)+8*(reg>>2)+4*hi within (fg*64+mi*32)
#pragma unroll
  for (int ni = 0; ni < 3; ++ni) {
    int n = narr[ni];
    if (n >= NPOS) continue;
    int b = n / OWOH;
    int r = n - b * OWOH;
    int w = r / OH_;
    int h = r - w * OH_;
    float* op = out + ((size_t)(b * F_) * OW_ + w) * OH_ + h;
#pragma unroll
    for (int mi = 0; mi < 2; ++mi) {
      const int fbase = fg * 64 + mi * 32 + 4 * hi;
#pragma unroll
      for (int reg = 0; reg < 16; ++reg) {
        int f = fbase + (reg & 3) + 8 * (reg >> 2);
        op[(size_t)f * OWOH] = acc[mi][ni][reg];
      }
    }
  }
}

// ---------------- correctness fallback (ws too small) ----------------
__global__ void naive_conv(const float* __restrict__ in, const float* __restrict__ ker,
                           float* __restrict__ out) {
  int idx = blockIdx.x * 256 + threadIdx.x;
  const int total = B_ * F_ * OW_ * OH_;
  if (idx >= total) return;
  int h = idx % OH_;
  int w = (idx / OH_) % OW_;
  int f = (idx / (OW_ * OH_)) % F_;
  int b = idx / (F_ * OW_ * OH_);
  float s = 0.f;
  for (int tap = 0; tap < 9; ++tap) {
    int i = tap / 3, j = tap % 3;
    const float* ip = in + ((size_t)b * C_ * H_ + (h + j)) * W_ + (w + i);
    const float* kp = ker + (size_t)f * KK_ + tap * C_;
    for (int c = 0; c < C_; ++c) s += ip[(size_t)c * HW_] * kp[c];
  }
  out[idx] = s;
}

extern "C" void kernel_launch(void* const* d_in, const int* in_sizes, int n_in,
                              void* d_out, int out_size, void* d_ws, size_t ws_size,
                              hipStream_t stream) {
  const float* in = (const float*)d_in[0];
  const float* ker = (const float*)d_in[1];
  float* out = (float*)d_out;

  const size_t xElems = (size_t)B_ * H_ * W_ * C_;  // 6,422,528
  const size_t need = (xElems + AELEMS) * 2;        // ~13 MB fp16

  if (ws_size < need) {
    int total = B_ * F_ * OW_ * OH_;
    naive_conv<<<(total + 255) / 256, 256, 0, stream>>>(in, ker, out);
    return;
  }

  u16* xT = (u16*)d_ws;
  u16* kT = xT + xElems;

  prep_all<<<932, 256, 0, stream>>>(in, ker, xT, kT);
  conv_mfma<<<NBLK, 512, 0, stream>>>(xT, kT, out);
}

// Round 17
// 39.952 us; speedup vs baseline: 1.0637x; 1.0637x over previous
//
#include <hip/hip_runtime.h>

typedef unsigned short u16;
typedef unsigned int u32;
typedef _Float16 f16x8 __attribute__((ext_vector_type(8)));
typedef float f32x16 __attribute__((ext_vector_type(16)));

#define B_ 8
#define C_ 64
#define H_ 112
#define W_ 112
#define HW_ 12544
#define F_ 128
#define OH_ 110
#define OW_ 110
#define OWOH 12100
#define NPOS 96800
#define KK_ 576
#define NT_ 384           // output positions per block
#define NBLK 253          // 253 blocks x 512 thr (128f x 384n): B read ONCE per n
#define OCTSTRIDE 802816  // B_*W_*H_*8 elems per c-oct plane
#define AELEMS 73728      // F_*KK_ fp16 elems = 144KB = whole A' in LDS

__device__ __forceinline__ void gl_lds16(const void* g, void* l) {
  __builtin_amdgcn_global_load_lds((const __attribute__((address_space(1))) void*)g,
                                   (__attribute__((address_space(3))) void*)l,
                                   16, 0, 0);
}

// ---- fused prep: blocks 0..895 transpose input; blocks 896..931 convert kernel ----
// xT [c_oct][b][w][h]{8c} fp16 ; kT A'[ko16][khalf][128f][8c] fp16 (32x32x16 frag order)
__global__ __launch_bounds__(256) void prep_all(const float* __restrict__ in,
                                                const float* __restrict__ k,
                                                u16* __restrict__ xT,
                                                u16* __restrict__ kT) {
  const int bid = blockIdx.x;
  const int tid = threadIdx.x;
  if (bid >= 896) {
    const int base = (bid - 896) * 2048;
#pragma unroll
    for (int t = 0; t < 8; ++t) {
      int idx = base + t * 256 + tid;
      int c = idx & 7;
      int f = (idx >> 3) & 127;
      int hf = (idx >> 10) & 1;
      int ko16 = idx >> 11;
      _Float16 h = (_Float16)k[f * KK_ + ko16 * 16 + hf * 8 + c];
      kT[idx] = __builtin_bit_cast(u16, h);
    }
    return;
  }
  __shared__ float tile[8][8][113];
  const int b = bid / 112;
  const int r = bid % 112;
  const int oct = r / 14;
  const int hs = (r % 14) * 8;

  for (int idx = tid; idx < 8 * 8 * 112; idx += 256) {
    int c = idx / 896;
    int rem = idx - c * 896;
    int h = rem / 112;
    int w = rem - h * 112;
    tile[c][h][w] = in[(((size_t)(b * 64 + oct * 8 + c)) * 112 + (hs + h)) * 112 + w];
  }
  __syncthreads();

  for (int idx = tid; idx < 896; idx += 256) {
    int w = idx >> 3;
    int h = idx & 7;
    f16x8 v;
#pragma unroll
    for (int c = 0; c < 8; ++c) v[c] = (_Float16)tile[c][h][w];
    size_t o = ((((size_t)oct * B_ + b) * W_ + w) * H_ + (hs + h)) * 8;
    *(f16x8*)(xT + o) = v;
  }
}

// ------------- main: 512-thr, 128f x 384n, WHOLE A' in 144KB LDS, B direct (once/n) -------------
// The untried cell of the traffic matrix: A in LDS (9 MB stage total) AND f unsplit
// (B L2 traffic 221 -> 111 MB, each n read by exactly one block). Per-wave shape is
// r13's proven 64f x 96n (acc 96 regs, ~2 waves/SIMD via 8 waves, 1 blk/CU at 144KB).
// Barrier-free K-loop + 1-step B prefetch (r13 skeleton). Frag reads 512B contiguous
// per 32-lane half: conflict-free.
__global__ __launch_bounds__(512, 2) void conv_mfma(
    const u16* __restrict__ xT, const u16* __restrict__ kT,
    float* __restrict__ out) {
  __shared__ u16 lds[AELEMS];  // 144KB

  const int tid = threadIdx.x;
  const int wave = tid >> 6;
  const int lane = tid & 63;
  const int l31 = lane & 31;
  const int hi = lane >> 5;
  const int fg = wave >> 2;  // f-group: 0 -> f0..63, 1 -> f64..127
  const int nw = wave & 3;   // n-wave

  const int nblk = blockIdx.x;
  const int n0 = nblk * NT_ + nw * 96;

  // ---- B addressing: per-lane position offsets, 3 x 32 = 96 n per wave
  int posOff[3];
#pragma unroll
  for (int ni = 0; ni < 3; ++ni) {
    int n = n0 + ni * 32 + l31;
    if (n >= NPOS) n = 0;
    int b = n / OWOH;
    int r = n - b * OWOH;
    int w = r / OH_;
    int h = r - w * OH_;
    posOff[ni] = ((b * W_ + w) * H_ + h) * 8;
  }

  // ---- step-0 B loads issued BEFORE the stage barrier (tap0: oct = t*2 + hi)
  f16x8 bcur[6];
#pragma unroll
  for (int ni = 0; ni < 3; ++ni)
#pragma unroll
    for (int t = 0; t < 2; ++t)
      bcur[ni * 2 + t] = *(const f16x8*)(xT + (t * 2 + hi) * OCTSTRIDE + posOff[ni]);

  // ---- stage ALL of A' into LDS: linear, 18 x 16B per thread (9216 chunks / 512 thr)
#pragma unroll
  for (int it = 0; it < 18; ++it) {
    const u32 off = (u32)((it * 512 + tid) * 16);
    gl_lds16((const char*)kT + off, (char*)lds + off);
  }
  __syncthreads();  // the ONLY barrier

  f32x16 acc[2][3] = {};

#pragma unroll
  for (int s = 0; s < 18; ++s) {
    // prefetch step s+1's B (consumed next iteration)
    f16x8 bnext[6];
    if (s < 17) {
      const int sn = s + 1;
      const int tapn = sn >> 1;
      const int halfn = sn & 1;
      const int in_ = tapn / 3;
      const int jn = tapn - in_ * 3;
      const int sShiftN = (in_ * H_ + jn) * 8;
#pragma unroll
      for (int ni = 0; ni < 3; ++ni)
#pragma unroll
        for (int t = 0; t < 2; ++t)
          bnext[ni * 2 + t] = *(const f16x8*)(xT + (halfn * 4 + t * 2 + hi) * OCTSTRIDE +
                                              posOff[ni] + sShiftN);
    }

    // A: 4 ds_read_b128; ko16 = s*2+t, elem = ((ko16*2+hi)*128 + fg*64 + mi*32 + l31)*8
    f16x8 ah[4];
#pragma unroll
    for (int t = 0; t < 2; ++t)
#pragma unroll
      for (int mi = 0; mi < 2; ++mi)
        ah[t * 2 + mi] =
            *(const f16x8*)&lds[((((s * 2 + t) * 2 + hi) << 7) + fg * 64 + mi * 32 + l31) * 8];

    // MFMAs consume bcur (loaded a full step ago)
#pragma unroll
    for (int t = 0; t < 2; ++t)
#pragma unroll
      for (int mi = 0; mi < 2; ++mi)
#pragma unroll
        for (int ni = 0; ni < 3; ++ni)
          acc[mi][ni] = __builtin_amdgcn_mfma_f32_32x32x16_f16(ah[t * 2 + mi], bcur[ni * 2 + t],
                                                               acc[mi][ni], 0, 0, 0);

    if (s < 17) {
#pragma unroll
      for (int q = 0; q < 6; ++q) bcur[q] = bnext[q];
    }
  }

  // epilogue: col = lane&31 -> n; row = (reg&3)+8*(reg>>2)+4*hi within (fg*64+mi*32)
#pragma unroll
  for (int ni = 0; ni < 3; ++ni) {
    int n = n0 + ni * 32 + l31;
    if (n >= NPOS) continue;
    int b = n / OWOH;
    int r = n - b * OWOH;
    int w = r / OH_;
    int h = r - w * OH_;
    float* op = out + ((size_t)(b * F_) * OW_ + w) * OH_ + h;
#pragma unroll
    for (int mi = 0; mi < 2; ++mi) {
      const int fbase = fg * 64 + mi * 32 + 4 * hi;
#pragma unroll
      for (int reg = 0; reg < 16; ++reg) {
        int f = fbase + (reg & 3) + 8 * (reg >> 2);
        op[(size_t)f * OWOH] = acc[mi][ni][reg];
      }
    }
  }
}

// ---------------- correctness fallback (ws too small) ----------------
__global__ void naive_conv(const float* __restrict__ in, const float* __restrict__ ker,
                           float* __restrict__ out) {
  int idx = blockIdx.x * 256 + threadIdx.x;
  const int total = B_ * F_ * OW_ * OH_;
  if (idx >= total) return;
  int h = idx % OH_;
  int w = (idx / OH_) % OW_;
  int f = (idx / (OW_ * OH_)) % F_;
  int b = idx / (F_ * OW_ * OH_);
  float s = 0.f;
  for (int tap = 0; tap < 9; ++tap) {
    int i = tap / 3, j = tap % 3;
    const float* ip = in + ((size_t)b * C_ * H_ + (h + j)) * W_ + (w + i);
    const float* kp = ker + (size_t)f * KK_ + tap * C_;
    for (int c = 0; c < C_; ++c) s += ip[(size_t)c * HW_] * kp[c];
  }
  out[idx] = s;
}

extern "C" void kernel_launch(void* const* d_in, const int* in_sizes, int n_in,
                              void* d_out, int out_size, void* d_ws, size_t ws_size,
                              hipStream_t stream) {
  const float* in = (const float*)d_in[0];
  const float* ker = (const float*)d_in[1];
  float* out = (float*)d_out;

  const size_t xElems = (size_t)B_ * H_ * W_ * C_;  // 6,422,528
  const size_t need = (xElems + AELEMS) * 2;        // ~13 MB fp16

  if (ws_size < need) {
    int total = B_ * F_ * OW_ * OH_;
    naive_conv<<<(total + 255) / 256, 256, 0, stream>>>(in, ker, out);
    return;
  }

  u16* xT = (u16*)d_ws;
  u16* kT = xT + xElems;

  prep_all<<<932, 256, 0, stream>>>(in, ker, xT, kT);
  conv_mfma<<<NBLK, 512, 0, stream>>>(xT, kT, out);
}